// Round 7
// baseline (138.150 us; speedup 1.0000x reference)
//
#include <hip/hip_runtime.h>

// out[b, i, j] = x[b, i + j];  B=128, L=8192, W=31, n_win = 8162.
// R6 LDS-staged kernel with ONE change: float4 stores are non-temporal
// (stream past L2). The 126.5 MB output has zero reuse; keeping it out of
// L2 avoids dirty-line churn and leaves L2 for the x re-reads.
// A/B vs R6: everything else identical.

constexpr int B_   = 128;
constexpr int L_   = 8192;
constexpr int W_   = 31;
constexpr int NWIN = L_ - (W_ - 1);               // 8162
constexpr int PERB = NWIN * W_;                   // 253022 floats per batch row
constexpr long long TOTAL = (long long)B_ * PERB; // 32,386,816 (div by 4)
constexpr int NVEC  = (int)(TOTAL / 4);           // 8,096,704 float4 stores
constexpr int BLOCK = 256;
constexpr int K     = 4;                          // float4s per thread
constexpr int CHUNK = BLOCK * K;                  // 1024 float4 = 4096 elements
constexpr int GRID  = (NVEC + CHUNK - 1) / CHUNK; // 7907
constexpr int ELEMS = CHUNK * 4;                  // 4096 elements per block
constexpr int SPAN  = 168;                        // LDS span per row (max needed 164)

typedef float f32x4 __attribute__((ext_vector_type(4)));

__global__ __launch_bounds__(BLOCK) void unfold_kernel(const float* __restrict__ x,
                                                       float* __restrict__ out) {
    __shared__ float lds[2 * SPAN];

    const unsigned o0 = blockIdx.x * (unsigned)ELEMS;       // first flat element
    const unsigned b  = o0 / (unsigned)PERB;                // magic-mul
    const unsigned q0 = o0 - b * (unsigned)PERB;            // within-row start
    const unsigned qL = (q0 + (unsigned)ELEMS - 1u < (unsigned)PERB - 1u)
                        ? (q0 + (unsigned)ELEMS - 1u) : ((unsigned)PERB - 1u);
    const unsigned i_lo = q0 / 31u;
    const unsigned i_hi = qL / 31u;
    const unsigned n0   = i_hi - i_lo + 31u;                // <= 164

    const float* __restrict__ xb = x + b * L_;
    for (unsigned k = threadIdx.x; k < n0; k += BLOCK)      // one pass: n0 < 256
        lds[k] = xb[i_lo + k];

    const bool straddle = (q0 + (unsigned)ELEMS > (unsigned)PERB) &&
                          (b + 1u < (unsigned)B_);
    if (straddle) {
        unsigned q1max = q0 + (unsigned)ELEMS - 1u - (unsigned)PERB; // <= 4094
        unsigned n1 = q1max / 31u + 31u;                    // <= 163
        const float* __restrict__ xb1 = xb + L_;
        for (unsigned k = threadIdx.x; k < n1; k += BLOCK)
            lds[SPAN + k] = xb1[k];
    }
    __syncthreads();

    unsigned t = blockIdx.x * CHUNK + threadIdx.x;          // float4 index
    unsigned q = q0 + 4u * threadIdx.x;                     // within-row element coord
    unsigned boff = 0, ibase = i_lo;
    bool sel1 = false;
    if (q >= (unsigned)PERB) {                              // thread starts in row b+1
        q -= (unsigned)PERB; sel1 = true; boff = SPAN; ibase = 0;
    }
    unsigned i = q / 31u;                                   // magic-mul, once
    unsigned j = q - 31u * i;
    f32x4* __restrict__ o4 = reinterpret_cast<f32x4*>(out);

#pragma unroll
    for (int s = 0; s < K; ++s) {
        if (t < (unsigned)NVEC) {
            f32x4 v;
            unsigned idx0 = boff + (i + j - ibase);         // lds idx of elem q
#pragma unroll
            for (int k = 0; k < 4; ++k) {
                unsigned jk  = j + (unsigned)k;
                unsigned idx = idx0 + (unsigned)k - (jk >= 31u ? 30u : 0u);
                if (!sel1 && q + (unsigned)k >= (unsigned)PERB)      // elem in row b+1
                    idx = (unsigned)SPAN + (q + (unsigned)k - (unsigned)PERB);
                v[k] = lds[idx];
            }
            __builtin_nontemporal_store(v, &o4[t]);         // <-- the one change
        }
        // advance one grid-step: +BLOCK float4 = +1024 elements = 33*31 + 1
        t += BLOCK;
        q += 1024u;
        if (!sel1 && q >= (unsigned)PERB) {                 // crossed into row b+1
            q -= (unsigned)PERB;                            // q < 1024 now
            sel1 = true; boff = SPAN; ibase = 0;
            i = q / 31u;                                    // rare magic-mul
            j = q - 31u * i;
        } else {
            i += 33u; j += 1u;
            if (j >= 31u) { j -= 31u; ++i; }                // single carry
        }
    }
}

extern "C" void kernel_launch(void* const* d_in, const int* in_sizes, int n_in,
                              void* d_out, int out_size, void* d_ws, size_t ws_size,
                              hipStream_t stream) {
    const float* x = (const float*)d_in[0];
    float* out = (float*)d_out;
    unfold_kernel<<<GRID, BLOCK, 0, stream>>>(x, out);
}

// Round 8
// 131.964 us; speedup vs baseline: 1.0469x; 1.0469x over previous
//
#include <hip/hip_runtime.h>

// out[b, i, j] = x[b, i + j];  B=128, L=8192, W=31, n_win = 8162.
// R6 LDS-staged kernel, restructured for block-overhead amortization + store ILP:
//   K=4 -> 16  (64 KB output per block; GRID 7907 -> 1977 ~= 7.7 blocks/CU,
//               so nearly all blocks are co-resident and staging latency is
//               paid once, overlapped, instead of 31x serially per CU)
//   __launch_bounds__(256, 8): cap VGPR <= 64, guarantee 8 blocks/CU
//   #pragma unroll 4: cluster ds_reads -> 1 waitcnt -> 4 independent stores
// Stores plain float4 (R7 showed NT neutral).

constexpr int B_   = 128;
constexpr int L_   = 8192;
constexpr int W_   = 31;
constexpr int NWIN = L_ - (W_ - 1);               // 8162
constexpr int PERB = NWIN * W_;                   // 253022 floats per batch row
constexpr long long TOTAL = (long long)B_ * PERB; // 32,386,816 (div by 4)
constexpr int NVEC  = (int)(TOTAL / 4);           // 8,096,704 float4 stores
constexpr int BLOCK = 256;
constexpr int K     = 16;                         // float4s per thread
constexpr int CHUNK = BLOCK * K;                  // 4096 float4 = 16384 elements
constexpr int GRID  = (NVEC + CHUNK - 1) / CHUNK; // 1977
constexpr int ELEMS = CHUNK * 4;                  // 16384 elements per block
constexpr int SPAN  = 576;                        // per-row LDS span (max needed 560)

typedef float f32x4 __attribute__((ext_vector_type(4)));

__global__ __launch_bounds__(BLOCK, 8) void unfold_kernel(const float* __restrict__ x,
                                                          float* __restrict__ out) {
    __shared__ float lds[2 * SPAN];

    const unsigned o0 = blockIdx.x * (unsigned)ELEMS;       // first flat element
    const unsigned b  = o0 / (unsigned)PERB;                // magic-mul
    const unsigned q0 = o0 - b * (unsigned)PERB;            // within-row start
    const unsigned qL = (q0 + (unsigned)ELEMS - 1u < (unsigned)PERB - 1u)
                        ? (q0 + (unsigned)ELEMS - 1u) : ((unsigned)PERB - 1u);
    const unsigned i_lo = q0 / 31u;
    const unsigned i_hi = qL / 31u;
    const unsigned n0   = i_hi - i_lo + 31u;                // <= 560

    const float* __restrict__ xb = x + b * L_;
    for (unsigned k = threadIdx.x; k < n0; k += BLOCK)      // <= 3 rounds
        lds[k] = xb[i_lo + k];

    const bool straddle = (q0 + (unsigned)ELEMS > (unsigned)PERB) &&
                          (b + 1u < (unsigned)B_);
    if (straddle) {
        unsigned q1max = q0 + (unsigned)ELEMS - 1u - (unsigned)PERB; // <= 16382
        unsigned n1 = q1max / 31u + 31u;                    // <= 559
        const float* __restrict__ xb1 = xb + L_;
        for (unsigned k = threadIdx.x; k < n1; k += BLOCK)
            lds[SPAN + k] = xb1[k];
    }
    __syncthreads();

    unsigned t = blockIdx.x * CHUNK + threadIdx.x;          // float4 index
    unsigned q = q0 + 4u * threadIdx.x;                     // within-row element coord
    unsigned boff = 0, ibase = i_lo;
    bool sel1 = false;
    if (q >= (unsigned)PERB) {                              // thread starts in row b+1
        q -= (unsigned)PERB; sel1 = true; boff = SPAN; ibase = 0;
    }
    unsigned i = q / 31u;                                   // magic-mul, once
    unsigned j = q - 31u * i;
    f32x4* __restrict__ o4 = reinterpret_cast<f32x4*>(out);

#pragma unroll 4
    for (int s = 0; s < K; ++s) {
        if (t < (unsigned)NVEC) {
            f32x4 v;
            unsigned idx0 = boff + (i + j - ibase);         // lds idx of elem q
#pragma unroll
            for (int k = 0; k < 4; ++k) {
                unsigned jk  = j + (unsigned)k;
                unsigned idx = idx0 + (unsigned)k - (jk >= 31u ? 30u : 0u);
                if (!sel1 && q + (unsigned)k >= (unsigned)PERB)      // elem in row b+1
                    idx = (unsigned)SPAN + (q + (unsigned)k - (unsigned)PERB);
                v[k] = lds[idx];
            }
            o4[t] = v;
        }
        // advance one grid-step: +BLOCK float4 = +1024 elements = 33*31 + 1
        t += BLOCK;
        q += 1024u;
        if (!sel1 && q >= (unsigned)PERB) {                 // crossed into row b+1
            q -= (unsigned)PERB;                            // q < 1024 now
            sel1 = true; boff = SPAN; ibase = 0;
            i = q / 31u;                                    // rare magic-mul
            j = q - 31u * i;
        } else {
            i += 33u; j += 1u;
            if (j >= 31u) { j -= 31u; ++i; }                // single carry
        }
    }
}

extern "C" void kernel_launch(void* const* d_in, const int* in_sizes, int n_in,
                              void* d_out, int out_size, void* d_ws, size_t ws_size,
                              hipStream_t stream) {
    const float* x = (const float*)d_in[0];
    float* out = (float*)d_out;
    unfold_kernel<<<GRID, BLOCK, 0, stream>>>(x, out);
}